// Round 1
// baseline (29198.343 us; speedup 1.0000x reference)
//
#include <hip/hip_runtime.h>
#include <cstdint>
#include <cstddef>

// ---------------------------------------------------------------------------
// TaggingFNNDecoder: 2-layer LSTM (H=512) with softmax-feedback over T=256.
// Round 0 plan:
//   * xpre_kernel: parallel fp32 GEMM for the non-recurrent x@W_ih0[:, :D].T
//     part (+ b_ih0 + b_hh0), chunked 16 timesteps at a time (4MB ws buffer).
//   * seq_kernel: cooperative persistent kernel, 256 blocks x 256 thr.
//     Per step: slot A (layer-0 LSTM) | grid-bar | slot B (layer-1 LSTM) |
//     grid-bar | slot C (logit+softmax, 32 blocks) | grid-bar.
//     Block j-partition: block owns hidden units j=2*bid..+1 of BOTH layers;
//     c-state lives in registers of threads 0..63 for the whole chunk.
//   * Custom sharded grid barrier (8 shards, agent-scope atomics, rel/acq).
// ---------------------------------------------------------------------------

#define Bz   32
#define Tz   256
#define Dz   1024
#define Hz   512
#define NK   128
#define IN0  (Dz + NK)      // 1152
#define CH   16             // timesteps per chunk
#define NBLK 256
#define BH   (Bz * Hz)      // 16384

// ---------------- sharded grid barrier (agent scope) ----------------
__device__ __forceinline__ void gbar(unsigned int* bar) {
  __syncthreads();
  if (threadIdx.x == 0) {
    unsigned int* shard = bar + (blockIdx.x & 7) * 512;   // 2KB-spaced shards
    unsigned int* root  = bar + 8 * 512;
    unsigned int* gen   = bar + 9 * 512;
    unsigned int g = __hip_atomic_load(gen, __ATOMIC_RELAXED, __HIP_MEMORY_SCOPE_AGENT);
    unsigned int a = __hip_atomic_fetch_add(shard, 1u, __ATOMIC_ACQ_REL, __HIP_MEMORY_SCOPE_AGENT);
    if ((a & 31u) == 31u) {                               // shard leader (32/shard)
      unsigned int r = __hip_atomic_fetch_add(root, 1u, __ATOMIC_ACQ_REL, __HIP_MEMORY_SCOPE_AGENT);
      if ((r & 7u) == 7u)                                 // last of 8 shards
        __hip_atomic_store(gen, g + 1u, __ATOMIC_RELEASE, __HIP_MEMORY_SCOPE_AGENT);
    }
    while (__hip_atomic_load(gen, __ATOMIC_ACQUIRE, __HIP_MEMORY_SCOPE_AGENT) == g)
      __builtin_amdgcn_s_sleep(1);
  }
  __syncthreads();
}

__device__ __forceinline__ float sigf(float x) { return 1.0f / (1.0f + expf(-x)); }

// stage hl[b][k] = src[b*stride + k0 + k], k in [0,KC)
__device__ __forceinline__ void stage_act(float (*hl)[260], const float* __restrict__ src,
                                          int stride, int k0, int KC) {
  const int tid = threadIdx.x;
  for (int e = tid * 4; e < 32 * KC; e += NBLK * 4) {
    int bb = e / KC;
    int kk = e - bb * KC;
    float4 v = *(const float4*)(src + (size_t)bb * stride + k0 + kk);
    *(float4*)&hl[bb][kk] = v;
  }
}

__device__ __forceinline__ float dot_chunk(const float (*hl)[260], int b,
                                           const float* __restrict__ wrow, int KC) {
  float acc = 0.0f;
  #pragma unroll 8
  for (int k = 0; k < KC; k += 4) {
    float4 h4 = *(const float4*)&hl[b][k];
    float4 w4 = *(const float4*)(wrow + k);
    acc += h4.x * w4.x + h4.y * w4.y + h4.z * w4.z + h4.w * w4.w;
  }
  return acc;
}

// output head + softmax for batch row bb. t==-1: init (sm only, no output).
__device__ void c_slot(const float* __restrict__ src, int t, int bb,
                       const float* __restrict__ W_out, const float* __restrict__ b_out,
                       const float* __restrict__ mask,
                       float* __restrict__ smg, float* __restrict__ out,
                       float (*cpart)[2], float* wred) {
  const int tid = threadIdx.x;
  const int n = tid & 127, kh = tid >> 7;
  float p = 0.0f;
  const float* w  = W_out + (size_t)n * Hz + kh * 256;
  const float* s2 = src + kh * 256;
  #pragma unroll 8
  for (int k = 0; k < 256; k += 4) {
    float4 sv = *(const float4*)(s2 + k);
    float4 wv = *(const float4*)(w + k);
    p += sv.x * wv.x + sv.y * wv.y + sv.z * wv.z + sv.w * wv.w;
  }
  cpart[n][kh] = p;
  __syncthreads();
  float logit = 0.0f;
  if (tid < 128) logit = cpart[n][0] + cpart[n][1] + b_out[n];
  // unmasked softmax -> sm (recurrent feedback)
  float m = logit;
  #pragma unroll
  for (int off = 32; off >= 1; off >>= 1) m = fmaxf(m, __shfl_xor(m, off));
  if ((tid & 63) == 0 && tid < 128) wred[tid >> 6] = m;
  __syncthreads();
  float M = fmaxf(wred[0], wred[1]);
  float e = (tid < 128) ? expf(logit - M) : 0.0f;
  float sfx = e;
  #pragma unroll
  for (int off = 32; off >= 1; off >>= 1) sfx += __shfl_xor(sfx, off);
  if ((tid & 63) == 0 && tid < 128) wred[2 + (tid >> 6)] = sfx;
  __syncthreads();
  float S = wred[2] + wred[3];
  if (tid < 128) smg[bb * NK + n] = e / S;

  if (t >= 0) {
    // masked softmax -> output probabilities (faithful to reference)
    float mk = mask[bb * Tz + t];
    float lm = (tid < 128) ? (logit + (1.0f - mk) * (-1e32f)) : 0.0f;
    float m2 = lm;
    #pragma unroll
    for (int off = 32; off >= 1; off >>= 1) m2 = fmaxf(m2, __shfl_xor(m2, off));
    if ((tid & 63) == 0 && tid < 128) wred[4 + (tid >> 6)] = m2;
    __syncthreads();
    float M2 = fmaxf(wred[4], wred[5]);
    float e2 = (tid < 128) ? expf(lm - M2) : 0.0f;
    float s2r = e2;
    #pragma unroll
    for (int off = 32; off >= 1; off >>= 1) s2r += __shfl_xor(s2r, off);
    if ((tid & 63) == 0 && tid < 128) wred[6 + (tid >> 6)] = s2r;
    __syncthreads();
    float S2 = wred[6] + wred[7];
    if (tid < 128) out[((size_t)bb * Tz + t) * NK + n] = e2 / S2;
  }
}

// ---------------- precompute GEMM: Xpre[n][cl] for one 16-step chunk -------
// Xpre[n][(t-t0)*32+b] = sum_k hiddens[b][t][k] * W_ih0[n][k] + b_ih0[n]+b_hh0[n]
__global__ void __launch_bounds__(256)
xpre_kernel(const float* __restrict__ hiddens, const float* __restrict__ W_ih0,
            const float* __restrict__ b_ih0, const float* __restrict__ b_hh0,
            float* __restrict__ Xpre, int t0) {
  __shared__ float Ws[16][64];
  __shared__ float Hs[16][64];
  const int tid = threadIdx.x;
  const int bx = blockIdx.x & 7;   // col tile (8 x 64 = 512 cols)
  const int by = blockIdx.x >> 3;  // n tile  (32 x 64 = 2048 rows)
  const int n0 = by * 64, c0 = bx * 64;
  const int tx = tid & 15, ty = tid >> 4;
  const int ldn = tid >> 2;        // 0..63
  const int ldk = (tid & 3) * 4;   // 0,4,8,12

  const int bb = ldn & 31;
  const int tt = t0 + (c0 >> 5) + (ldn >> 5);
  const float* hsrc = hiddens + ((size_t)bb * Tz + tt) * Dz + ldk;
  const float* wsrc = W_ih0 + (size_t)(n0 + ldn) * IN0 + ldk;

  float acc[4][4] = {};
  float4 wv = *(const float4*)(wsrc);
  float4 hv = *(const float4*)(hsrc);
  for (int k0 = 0; k0 < Dz; k0 += 16) {
    __syncthreads();
    Ws[ldk + 0][ldn] = wv.x; Ws[ldk + 1][ldn] = wv.y;
    Ws[ldk + 2][ldn] = wv.z; Ws[ldk + 3][ldn] = wv.w;
    Hs[ldk + 0][ldn] = hv.x; Hs[ldk + 1][ldn] = hv.y;
    Hs[ldk + 2][ldn] = hv.z; Hs[ldk + 3][ldn] = hv.w;
    __syncthreads();
    if (k0 + 16 < Dz) {   // prefetch next tiles while computing
      wv = *(const float4*)(wsrc + k0 + 16);
      hv = *(const float4*)(hsrc + k0 + 16);
    }
    #pragma unroll
    for (int k = 0; k < 16; ++k) {
      float4 a4 = *(const float4*)&Ws[k][ty * 4];
      float4 b4 = *(const float4*)&Hs[k][tx * 4];
      acc[0][0] += a4.x * b4.x; acc[0][1] += a4.x * b4.y; acc[0][2] += a4.x * b4.z; acc[0][3] += a4.x * b4.w;
      acc[1][0] += a4.y * b4.x; acc[1][1] += a4.y * b4.y; acc[1][2] += a4.y * b4.z; acc[1][3] += a4.y * b4.w;
      acc[2][0] += a4.z * b4.x; acc[2][1] += a4.z * b4.y; acc[2][2] += a4.z * b4.z; acc[2][3] += a4.z * b4.w;
      acc[3][0] += a4.w * b4.x; acc[3][1] += a4.w * b4.y; acc[3][2] += a4.w * b4.z; acc[3][3] += a4.w * b4.w;
    }
  }
  #pragma unroll
  for (int i = 0; i < 4; ++i) {
    int n = n0 + ty * 4 + i;
    float bi = b_ih0[n] + b_hh0[n];
    float4 v = make_float4(acc[i][0] + bi, acc[i][1] + bi, acc[i][2] + bi, acc[i][3] + bi);
    *(float4*)(Xpre + (size_t)n * (CH * 32) + c0 + tx * 4) = v;
  }
}

// ---------------- sequential cooperative kernel (16 steps/launch) ----------
__global__ void __launch_bounds__(256)
seq_kernel(const float* __restrict__ hiddens,
           const float* __restrict__ h_t, const float* __restrict__ c_t,
           const float* __restrict__ mask,
           const float* __restrict__ W_out, const float* __restrict__ b_out,
           const float* __restrict__ W_ih0, const float* __restrict__ W_hh0,
           const float* __restrict__ W_ih1, const float* __restrict__ W_hh1,
           const float* __restrict__ b_ih1, const float* __restrict__ b_hh1,
           const float* __restrict__ Xpre, float* __restrict__ out,
           float* __restrict__ h1g, float* __restrict__ h2g,
           float* __restrict__ smg, float* __restrict__ c1g, float* __restrict__ c2g,
           unsigned int* bar, int t0, int isFirst) {
  __shared__ float hl[32][260];     // padded: +4 keeps float4 rows 16B-aligned
  __shared__ float gbuf[8][32];
  __shared__ float cpart[128][2];
  __shared__ float wred[8];

  const int tid  = threadIdx.x;
  const int b    = tid & 31;
  const int ng   = tid >> 5;        // 0..7
  const int gate = ng >> 1;
  const int jj   = ng & 1;
  const int j0   = blockIdx.x * 2;
  const int rA   = gate * Hz + j0 + jj;   // gate row in [0, 4H)

  // cell-state registers: threads 0..63 own (b=cb, j=j0+cj) for BOTH layers
  const int cb = tid & 31;
  const int cj = (tid >> 5) & 1;
  const int jc = j0 + cj;
  float c1r = 0.0f, c2r = 0.0f;
  if (tid < 64) {
    if (isFirst) {
      c1r = c_t[cb * Hz + jc];
      c2r = c_t[BH + cb * Hz + jc];
    } else {
      c1r = c1g[cb * Hz + jc];
      c2r = c2g[cb * Hz + jc];
    }
  }

  if (isFirst) {
    // h state init into parity-1 buffers
    int fid = blockIdx.x * NBLK + tid;
    if (fid < BH) {
      h1g[BH + fid] = h_t[fid];
      h2g[BH + fid] = h_t[BH + fid];
    }
    gbar(bar);
    if (blockIdx.x < 32)   // sm(-1) from hiddens[:,0,:H]
      c_slot(hiddens + (size_t)blockIdx.x * Tz * Dz, -1, blockIdx.x,
             W_out, b_out, mask, smg, out, cpart, wred);
    gbar(bar);
  }

  for (int s = 0; s < CH; ++s) {
    const int t = t0 + s;
    const float* h1prev = h1g + ((t + 1) & 1) * BH;
    float*       h1cur  = h1g + (t & 1) * BH;
    const float* h2prev = h2g + ((t + 1) & 1) * BH;
    float*       h2cur  = h2g + (t & 1) * BH;

    // ---- slot A: layer-0 LSTM (gates += h1_prev@W_hh0.T + sm@W_sm.T) ----
    {
      float acc = Xpre[(size_t)rA * (CH * 32) + s * 32 + b];
      stage_act(hl, h1prev, Hz, 0, 256); __syncthreads();
      acc += dot_chunk(hl, b, W_hh0 + (size_t)rA * Hz, 256); __syncthreads();
      stage_act(hl, h1prev, Hz, 256, 256); __syncthreads();
      acc += dot_chunk(hl, b, W_hh0 + (size_t)rA * Hz + 256, 256); __syncthreads();
      stage_act(hl, smg, NK, 0, 128); __syncthreads();
      acc += dot_chunk(hl, b, W_ih0 + (size_t)rA * IN0 + Dz, 128);
      gbuf[ng][b] = acc;
      __syncthreads();
      if (tid < 64) {
        float gi = gbuf[cj][cb], gf = gbuf[2 + cj][cb];
        float gg = gbuf[4 + cj][cb], go = gbuf[6 + cj][cb];
        c1r = sigf(gf) * c1r + sigf(gi) * tanhf(gg);
        h1cur[cb * Hz + jc] = sigf(go) * tanhf(c1r);
      }
    }
    gbar(bar);

    // ---- slot B: layer-1 LSTM (gates = h1@W_ih1.T + h2_prev@W_hh1.T) ----
    {
      float acc = b_ih1[rA] + b_hh1[rA];
      stage_act(hl, h1cur, Hz, 0, 256); __syncthreads();
      acc += dot_chunk(hl, b, W_ih1 + (size_t)rA * Hz, 256); __syncthreads();
      stage_act(hl, h1cur, Hz, 256, 256); __syncthreads();
      acc += dot_chunk(hl, b, W_ih1 + (size_t)rA * Hz + 256, 256); __syncthreads();
      stage_act(hl, h2prev, Hz, 0, 256); __syncthreads();
      acc += dot_chunk(hl, b, W_hh1 + (size_t)rA * Hz, 256); __syncthreads();
      stage_act(hl, h2prev, Hz, 256, 256); __syncthreads();
      acc += dot_chunk(hl, b, W_hh1 + (size_t)rA * Hz + 256, 256);
      gbuf[ng][b] = acc;
      __syncthreads();
      if (tid < 64) {
        float gi = gbuf[cj][cb], gf = gbuf[2 + cj][cb];
        float gg = gbuf[4 + cj][cb], go = gbuf[6 + cj][cb];
        c2r = sigf(gf) * c2r + sigf(gi) * tanhf(gg);
        h2cur[cb * Hz + jc] = sigf(go) * tanhf(c2r);
      }
    }
    gbar(bar);

    // ---- slot C: logits + softmax + output ----
    if (blockIdx.x < 32)
      c_slot(h2cur + (size_t)blockIdx.x * Hz, t, blockIdx.x,
             W_out, b_out, mask, smg, out, cpart, wred);
    gbar(bar);
  }

  if (tid < 64) {   // spill cell state for next chunk
    c1g[cb * Hz + jc] = c1r;
    c2g[cb * Hz + jc] = c2r;
  }
}

// ---------------------------------------------------------------------------
extern "C" void kernel_launch(void* const* d_in, const int* in_sizes, int n_in,
                              void* d_out, int out_size, void* d_ws, size_t ws_size,
                              hipStream_t stream) {
  (void)in_sizes; (void)n_in; (void)out_size; (void)ws_size;
  const float* hiddens = (const float*)d_in[0];
  const float* h_t     = (const float*)d_in[1];
  const float* c_t     = (const float*)d_in[2];
  const float* mask    = (const float*)d_in[3];
  const float* W_out   = (const float*)d_in[4];
  const float* b_out   = (const float*)d_in[5];
  const float* W_ih0   = (const float*)d_in[6];
  const float* W_hh0   = (const float*)d_in[7];
  const float* b_ih0   = (const float*)d_in[8];
  const float* b_hh0   = (const float*)d_in[9];
  const float* W_ih1   = (const float*)d_in[10];
  const float* W_hh1   = (const float*)d_in[11];
  const float* b_ih1   = (const float*)d_in[12];
  const float* b_hh1   = (const float*)d_in[13];
  float* out = (float*)d_out;

  // workspace layout (~4.42 MB)
  unsigned int* bar = (unsigned int*)d_ws;           // 10*512 uints = 20480 B
  float* base = (float*)((char*)d_ws + 20480);
  float* Xpre = base;                                // 2048*512
  float* h1g  = Xpre + 2048 * (CH * 32);             // 2*BH (parity)
  float* h2g  = h1g + 2 * BH;                        // 2*BH
  float* smg  = h2g + 2 * BH;                        // Bz*NK
  float* c1g  = smg + Bz * NK;                       // BH
  float* c2g  = c1g + BH;                            // BH

  hipMemsetAsync(bar, 0, 20480, stream);

  for (int c = 0; c < Tz / CH; ++c) {
    int t0 = c * CH;
    int isFirst = (c == 0) ? 1 : 0;
    hipLaunchKernelGGL(xpre_kernel, dim3(NBLK), dim3(256), 0, stream,
                       hiddens, W_ih0, b_ih0, b_hh0, Xpre, t0);
    void* ka[] = { (void*)&hiddens, (void*)&h_t, (void*)&c_t, (void*)&mask,
                   (void*)&W_out, (void*)&b_out, (void*)&W_ih0, (void*)&W_hh0,
                   (void*)&W_ih1, (void*)&W_hh1, (void*)&b_ih1, (void*)&b_hh1,
                   (void*)&Xpre, (void*)&out, (void*)&h1g, (void*)&h2g,
                   (void*)&smg, (void*)&c1g, (void*)&c2g, (void*)&bar,
                   (void*)&t0, (void*)&isFirst };
    hipLaunchCooperativeKernel((void*)seq_kernel, dim3(NBLK), dim3(256), ka, 0, stream);
  }
}

// Round 2
// 17932.501 us; speedup vs baseline: 1.6282x; 1.6282x over previous
//
#include <hip/hip_runtime.h>
#include <cstdint>
#include <cstddef>

// ---------------------------------------------------------------------------
// TaggingFNNDecoder round 2: single persistent cooperative kernel.
//  * Weights LDS-resident: block b owns hidden units j={2b,2b+1} of both
//    LSTM layers -> 8 gate rows/layer. wA rows = [W_hh0 | W_ih0_x | W_ih0_sm]
//    (1664), wB rows = [W_ih1 | W_hh1] (1024). Loaded from HBM once.
//  * x@W_ih0 inlined into slot A (no xpre kernel, no Xpre buffer).
//  * Fast grid barrier: release-STORE arrivals to private cachelines,
//    checker block scans with RELAXED system loads (no per-poll invalidate),
//    single ACQUIRE per block at exit. Round-1 barrier (~36us) was killed by
//    acquire-per-poll buffer_inv storms + RMW serialization.
//  * Cell state c1/c2 lives in registers of threads 0..63 for all 256 steps.
// ---------------------------------------------------------------------------

#define Bz   32
#define Tz   256
#define Dz   1024
#define Hz   512
#define NK   128
#define IN0  (Dz + NK)      // 1152
#define NBLK 256
#define BH   (Bz * Hz)      // 16384

// ---------------- fast grid barrier ----------------
// bar layout: slot[b] at bar + b*16 (64B spacing), gen at bar + NBLK*16.
// g increases monotonically (1,2,3,...) across the whole launch.
__device__ __forceinline__ void gbar(unsigned int* bar, unsigned int g) {
  __syncthreads();
  const int bid = blockIdx.x;
  unsigned int* gen = bar + NBLK * 16;
  if (threadIdx.x == 0)
    __hip_atomic_store(bar + bid * 16, g, __ATOMIC_RELEASE, __HIP_MEMORY_SCOPE_AGENT);
  if (bid == NBLK - 1) {
    // checker: 256 lanes each watch one slot; RELAXED polls (no inv per poll)
    unsigned int* ws = bar + threadIdx.x * 16;
    while (__hip_atomic_load(ws, __ATOMIC_RELAXED, __HIP_MEMORY_SCOPE_SYSTEM) < g)
      __builtin_amdgcn_s_sleep(1);
    __syncthreads();
    if (threadIdx.x == 0)
      __hip_atomic_store(gen, g, __ATOMIC_RELEASE, __HIP_MEMORY_SCOPE_AGENT);
  }
  if (threadIdx.x == 0) {
    while (__hip_atomic_load(gen, __ATOMIC_RELAXED, __HIP_MEMORY_SCOPE_SYSTEM) < g)
      __builtin_amdgcn_s_sleep(2);
    (void)__hip_atomic_load(gen, __ATOMIC_ACQUIRE, __HIP_MEMORY_SCOPE_AGENT); // one inv
  }
  __syncthreads();
}

__device__ __forceinline__ float sigf(float x) { return 1.0f / (1.0f + expf(-x)); }

// ---- staging helpers: regs -> LDS act buffer hl[32][260] ----
__device__ __forceinline__ void store_seg(float (*hl)[260], const float4* rg,
                                          int nIt, int shift, int tid) {
  const int msk = (1 << shift) - 1;
  #pragma unroll
  for (int i = 0; i < 8; ++i) {
    if (i < nIt) {
      int e = tid * 4 + i * 1024;
      *(float4*)&hl[e >> shift][e & msk] = rg[i];
    }
  }
}

// output head + softmax for batch row bb. t==-1: init (sm only, no output).
__device__ void c_slot(const float* __restrict__ src, int t, int bb,
                       const float* __restrict__ W_out, const float* __restrict__ b_out,
                       const float* __restrict__ mask,
                       float* __restrict__ smg, float* __restrict__ out,
                       float (*cpart)[2], float* wred) {
  const int tid = threadIdx.x;
  const int n = tid & 127, kh = tid >> 7;
  float p = 0.0f;
  const float* w  = W_out + (size_t)n * Hz + kh * 256;
  const float* s2 = src + kh * 256;
  #pragma unroll 8
  for (int k = 0; k < 256; k += 4) {
    float4 sv = *(const float4*)(s2 + k);
    float4 wv = *(const float4*)(w + k);
    p += sv.x * wv.x + sv.y * wv.y + sv.z * wv.z + sv.w * wv.w;
  }
  cpart[n][kh] = p;
  __syncthreads();
  float logit = 0.0f;
  if (tid < 128) logit = cpart[n][0] + cpart[n][1] + b_out[n];
  float m = logit;
  #pragma unroll
  for (int off = 32; off >= 1; off >>= 1) m = fmaxf(m, __shfl_xor(m, off));
  if ((tid & 63) == 0 && tid < 128) wred[tid >> 6] = m;
  __syncthreads();
  float M = fmaxf(wred[0], wred[1]);
  float e = (tid < 128) ? expf(logit - M) : 0.0f;
  float sfx = e;
  #pragma unroll
  for (int off = 32; off >= 1; off >>= 1) sfx += __shfl_xor(sfx, off);
  if ((tid & 63) == 0 && tid < 128) wred[2 + (tid >> 6)] = sfx;
  __syncthreads();
  float S = wred[2] + wred[3];
  if (tid < 128) smg[bb * NK + n] = e / S;

  if (t >= 0) {
    float mk = mask[bb * Tz + t];
    float lm = (tid < 128) ? (logit + (1.0f - mk) * (-1e32f)) : 0.0f;
    float m2 = lm;
    #pragma unroll
    for (int off = 32; off >= 1; off >>= 1) m2 = fmaxf(m2, __shfl_xor(m2, off));
    if ((tid & 63) == 0 && tid < 128) wred[4 + (tid >> 6)] = m2;
    __syncthreads();
    float M2 = fmaxf(wred[4], wred[5]);
    float e2 = (tid < 128) ? expf(lm - M2) : 0.0f;
    float s2r = e2;
    #pragma unroll
    for (int off = 32; off >= 1; off >>= 1) s2r += __shfl_xor(s2r, off);
    if ((tid & 63) == 0 && tid < 128) wred[6 + (tid >> 6)] = s2r;
    __syncthreads();
    float S2 = wred[6] + wred[7];
    if (tid < 128) out[((size_t)bb * Tz + t) * NK + n] = e2 / S2;
  }
}

// ---------------- the persistent kernel ----------------
__global__ void __launch_bounds__(256)
seq_kernel(const float* __restrict__ hiddens,
           const float* __restrict__ h_t, const float* __restrict__ c_t,
           const float* __restrict__ mask,
           const float* __restrict__ W_out, const float* __restrict__ b_out,
           const float* __restrict__ W_ih0, const float* __restrict__ W_hh0,
           const float* __restrict__ b_ih0, const float* __restrict__ b_hh0,
           const float* __restrict__ W_ih1, const float* __restrict__ W_hh1,
           const float* __restrict__ b_ih1, const float* __restrict__ b_hh1,
           float* __restrict__ out,
           float* __restrict__ h1g, float* __restrict__ h2g,
           float* __restrict__ smg, unsigned int* bar) {
  // LDS: 53.4K + 32.9K + 33.3K + ~2.1K = ~121.7 KB (fits 160 KB/CU)
  __shared__ float wA[8][1668];   // pad: 1668%32=4 -> rows land on distinct banks
  __shared__ float wB[8][1028];
  __shared__ float bA[8], bB[8];
  __shared__ float hl[32][260];
  __shared__ float gbuf[8][32];
  __shared__ float cpart[128][2];
  __shared__ float wred[8];

  const int tid  = threadIdx.x;
  const int bid  = blockIdx.x;
  const int lane = tid & 63;
  const int w    = tid >> 6;
  // lane map: 4 rows x 16 batches per wave. Weight reads are 16-way
  // same-address (free broadcast); act reads 4-way same-address.
  const int row = (w >> 1) * 4 + (lane & 3);       // 0..7 = gate*2 + jj
  const int bb  = (w & 1) * 16 + (lane >> 2);      // 0..31

  // ---- one-time: weights into LDS ----
  #pragma unroll
  for (int r = 0; r < 8; ++r) {
    const int gate = r >> 1, jj = r & 1;
    const int rA = gate * Hz + 2 * bid + jj;
    for (int e = tid * 4; e < 512; e += 1024)
      *(float4*)&wA[r][e] = *(const float4*)(W_hh0 + (size_t)rA * Hz + e);
    for (int e = tid * 4; e < 1024; e += 1024)
      *(float4*)&wA[r][512 + e] = *(const float4*)(W_ih0 + (size_t)rA * IN0 + e);
    for (int e = tid * 4; e < 128; e += 1024)
      *(float4*)&wA[r][1536 + e] = *(const float4*)(W_ih0 + (size_t)rA * IN0 + 1024 + e);
    for (int e = tid * 4; e < 512; e += 1024)
      *(float4*)&wB[r][e] = *(const float4*)(W_ih1 + (size_t)rA * Hz + e);
    for (int e = tid * 4; e < 512; e += 1024)
      *(float4*)&wB[r][512 + e] = *(const float4*)(W_hh1 + (size_t)rA * Hz + e);
    if (tid == 0) {
      bA[r] = b_ih0[rA] + b_hh0[rA];
      bB[r] = b_ih1[rA] + b_hh1[rA];
    }
  }

  // ---- cell state in registers for the whole sequence ----
  const int cb = tid & 31;
  const int cj = (tid >> 5) & 1;
  const int jc = 2 * bid + cj;
  float c1r = 0.0f, c2r = 0.0f;
  if (tid < 64) {
    c1r = c_t[cb * Hz + jc];
    c2r = c_t[BH + cb * Hz + jc];
  }

  // ---- init: h state into parity-1 buffers; sm(-1) ----
  {
    int fid = bid * 256 + tid;
    if (fid < BH) {
      h1g[BH + fid] = h_t[fid];
      h2g[BH + fid] = h_t[BH + fid];
    }
  }
  if (bid < 32)
    c_slot(hiddens + (size_t)bid * Tz * Dz, -1, bid,
           W_out, b_out, mask, smg, out, cpart, wred);
  unsigned int g = 1;
  gbar(bar, g++);

  for (int t = 0; t < Tz; ++t) {
    const float* h1prev = h1g + ((t + 1) & 1) * BH;
    float*       h1cur  = h1g + (t & 1) * BH;
    const float* h2prev = h2g + ((t + 1) & 1) * BH;
    float*       h2cur  = h2g + (t & 1) * BH;

    // ---- slot A: layer-0 gates over acts [h1prev(512) | x_t(1024) | sm(128)]
    {
      float4 acc = make_float4(0.f, 0.f, 0.f, 0.f);
      float4 rg[8];
      // prologue: load seg 0
      #pragma unroll
      for (int i = 0; i < 8; ++i) {
        int e = tid * 4 + i * 1024;
        rg[i] = *(const float4*)(h1prev + (e >> 8) * Hz + (e & 255));
      }
      for (int s = 0; s < 7; ++s) {
        __syncthreads();                       // hl free
        store_seg(hl, rg, (s == 6) ? 4 : 8, (s == 6) ? 7 : 8, tid);
        __syncthreads();                       // hl ready
        if (s < 6) {                           // issue next seg's loads
          int sn = s + 1;
          if (sn == 6) {
            #pragma unroll
            for (int i = 0; i < 4; ++i) {
              int e = tid * 4 + i * 1024;
              rg[i] = *(const float4*)(smg + (e >> 7) * NK + (e & 127));
            }
          } else if (sn >= 2) {
            const float* src = hiddens + (size_t)t * Dz + (sn - 2) * 256;
            #pragma unroll
            for (int i = 0; i < 8; ++i) {
              int e = tid * 4 + i * 1024;
              rg[i] = *(const float4*)(src + (size_t)(e >> 8) * Tz * Dz + (e & 255));
            }
          } else {
            #pragma unroll
            for (int i = 0; i < 8; ++i) {
              int e = tid * 4 + i * 1024;
              rg[i] = *(const float4*)(h1prev + 256 + (e >> 8) * Hz + (e & 255));
            }
          }
        }
        const float* wr = &wA[row][s * 256];
        const float* ar = hl[bb];
        const int n4 = (s == 6) ? 32 : 64;
        #pragma unroll 8
        for (int k = 0; k < n4; ++k) {
          float4 a4 = *(const float4*)(ar + 4 * k);
          float4 w4 = *(const float4*)(wr + 4 * k);
          acc.x += a4.x * w4.x; acc.y += a4.y * w4.y;
          acc.z += a4.z * w4.z; acc.w += a4.w * w4.w;
        }
      }
      gbuf[row][bb] = acc.x + acc.y + acc.z + acc.w + bA[row];
      __syncthreads();
      if (tid < 64) {
        float gi = gbuf[0 + cj][cb], gf = gbuf[2 + cj][cb];
        float gg = gbuf[4 + cj][cb], go = gbuf[6 + cj][cb];
        c1r = sigf(gf) * c1r + sigf(gi) * tanhf(gg);
        h1cur[cb * Hz + jc] = sigf(go) * tanhf(c1r);
      }
    }
    gbar(bar, g++);

    // ---- slot B: layer-1 gates over acts [h1cur(512) | h2prev(512)] ----
    {
      float4 acc = make_float4(0.f, 0.f, 0.f, 0.f);
      float4 rg[8];
      #pragma unroll
      for (int i = 0; i < 8; ++i) {
        int e = tid * 4 + i * 1024;
        rg[i] = *(const float4*)(h1cur + (e >> 8) * Hz + (e & 255));
      }
      for (int s = 0; s < 4; ++s) {
        __syncthreads();
        store_seg(hl, rg, 8, 8, tid);
        __syncthreads();
        if (s < 3) {
          const float* src = (s + 1 < 2) ? (h1cur + (s + 1) * 256)
                                         : (h2prev + (s - 1) * 256);
          #pragma unroll
          for (int i = 0; i < 8; ++i) {
            int e = tid * 4 + i * 1024;
            rg[i] = *(const float4*)(src + (e >> 8) * Hz + (e & 255));
          }
        }
        const float* wr = &wB[row][s * 256];
        const float* ar = hl[bb];
        #pragma unroll 8
        for (int k = 0; k < 64; ++k) {
          float4 a4 = *(const float4*)(ar + 4 * k);
          float4 w4 = *(const float4*)(wr + 4 * k);
          acc.x += a4.x * w4.x; acc.y += a4.y * w4.y;
          acc.z += a4.z * w4.z; acc.w += a4.w * w4.w;
        }
      }
      gbuf[row][bb] = acc.x + acc.y + acc.z + acc.w + bB[row];
      __syncthreads();
      if (tid < 64) {
        float gi = gbuf[0 + cj][cb], gf = gbuf[2 + cj][cb];
        float gg = gbuf[4 + cj][cb], go = gbuf[6 + cj][cb];
        c2r = sigf(gf) * c2r + sigf(gi) * tanhf(gg);
        h2cur[cb * Hz + jc] = sigf(go) * tanhf(c2r);
      }
    }
    gbar(bar, g++);

    // ---- slot C: logits + softmax + output (32 blocks) ----
    if (bid < 32)
      c_slot(h2cur + (size_t)bid * Hz, t, bid,
             W_out, b_out, mask, smg, out, cpart, wred);
    gbar(bar, g++);
  }
}

// ---------------------------------------------------------------------------
extern "C" void kernel_launch(void* const* d_in, const int* in_sizes, int n_in,
                              void* d_out, int out_size, void* d_ws, size_t ws_size,
                              hipStream_t stream) {
  (void)in_sizes; (void)n_in; (void)out_size; (void)ws_size;
  const float* hiddens = (const float*)d_in[0];
  const float* h_t     = (const float*)d_in[1];
  const float* c_t     = (const float*)d_in[2];
  const float* mask    = (const float*)d_in[3];
  const float* W_out   = (const float*)d_in[4];
  const float* b_out   = (const float*)d_in[5];
  const float* W_ih0   = (const float*)d_in[6];
  const float* W_hh0   = (const float*)d_in[7];
  const float* b_ih0   = (const float*)d_in[8];
  const float* b_hh0   = (const float*)d_in[9];
  const float* W_ih1   = (const float*)d_in[10];
  const float* W_hh1   = (const float*)d_in[11];
  const float* b_ih1   = (const float*)d_in[12];
  const float* b_hh1   = (const float*)d_in[13];
  float* out = (float*)d_out;

  // ws: barrier (slots + gen) then state buffers
  unsigned int* bar = (unsigned int*)d_ws;               // (256*16+16)*4 B
  float* base = (float*)((char*)d_ws + 32768);
  float* h1g  = base;                                    // 2*BH (parity)
  float* h2g  = h1g + 2 * BH;                            // 2*BH
  float* smg  = h2g + 2 * BH;                            // Bz*NK

  hipMemsetAsync(bar, 0, 32768, stream);

  void* ka[] = { (void*)&hiddens, (void*)&h_t, (void*)&c_t, (void*)&mask,
                 (void*)&W_out, (void*)&b_out, (void*)&W_ih0, (void*)&W_hh0,
                 (void*)&b_ih0, (void*)&b_hh0, (void*)&W_ih1, (void*)&W_hh1,
                 (void*)&b_ih1, (void*)&b_hh1, (void*)&out,
                 (void*)&h1g, (void*)&h2g, (void*)&smg, (void*)&bar };
  hipLaunchCooperativeKernel((void*)seq_kernel, dim3(NBLK), dim3(256), ka, 0, stream);
}